// Round 3
// baseline (160.246 us; speedup 1.0000x reference)
//
#include <hip/hip_runtime.h>
#include <math.h>

#define EPSV 1e-5f

static constexpr int Ls = 2048, Hh = 8;
static constexpr int NCH = 64, T = 32;   // 64 chunks of 32 along L

typedef unsigned short u16;
using frag  = __attribute__((ext_vector_type(8))) short;   // 8 x bf16 (4 VGPRs)
using f32x4 = __attribute__((ext_vector_type(4))) float;

__device__ __forceinline__ void split_bf16(float v, u16& hi, u16& lo) {
    const unsigned u = __float_as_uint(v);
    hi = (u16)(u >> 16);
    const float hf = __uint_as_float((unsigned)hi << 16);
    lo = (u16)(__float_as_uint(v - hf) >> 16);
}

__device__ __forceinline__ unsigned pk2(u16 a, u16 b) {
    return (unsigned)a | ((unsigned)b << 16);
}

// split 8 fp32 into one uint4 of hi-bf16 and one uint4 of lo-bf16
__device__ __forceinline__ void split8(const float4& a, const float4& b,
                                       uint4& hi, uint4& lo) {
    u16 h[8], l[8];
    const float f[8] = {a.x, a.y, a.z, a.w, b.x, b.y, b.z, b.w};
#pragma unroll
    for (int i = 0; i < 8; ++i) split_bf16(f[i], h[i], l[i]);
    hi = make_uint4(pk2(h[0], h[1]), pk2(h[2], h[3]), pk2(h[4], h[5]), pk2(h[6], h[7]));
    lo = make_uint4(pk2(l[0], l[1]), pk2(l[2], l[3]), pk2(l[4], l[5]), pk2(l[6], l[7]));
}

// =====================================================================
// qkv_fused: split-bf16 MFMA GEMM for q,k,v (32 rows x 2 heads per block)
// + fused chunk_sum epilogue (normalize, sim, gate, chunk-Z, (m,s,g) totals)
// grid: (128 row-tiles, 4 head-pairs) x 256 threads (4 waves).
// LDS trimmed to ~36.4 KB (wkS aliased into smemf, filled post-GEMM) ->
// 4 blocks/CU = 4 waves/SIMD; __launch_bounds__(256,4) caps VGPR at 128.
// =====================================================================
__global__ __launch_bounds__(256, 4) void qkv_fused(
    const float* __restrict__ x,
    const float* __restrict__ wq, const float* __restrict__ wk, const float* __restrict__ wv,
    const float* __restrict__ bq, const float* __restrict__ bk, const float* __restrict__ bv,
    const float* __restrict__ wg_w, const float* __restrict__ wg_b,
    const float* __restrict__ kvs, const float* __restrict__ qks,
    float* __restrict__ qh, float* __restrict__ kh, float* __restrict__ vh,
    float* __restrict__ simG, float* __restrict__ gG,
    float* __restrict__ ZcT, float* __restrict__ mT, float* __restrict__ sT,
    float* __restrict__ gTt)
{
    constexpr int LDK = 40;     // u16 per staged row (80 B, 16B-aligned)
    constexpr int LDT = 66;     // f32 per tile row (264 B: 8B-aligned, 2-way banks)
    // one region, three overlapping uses separated by barriers:
    //   staging (35840 B) during GEMM; tiles (25344 B = f32[0,6336)) +
    //   wkS (8192 B = f32[6336,8384)) after GEMM.
    __shared__ __align__(16) float smemf[8960];
    __shared__ float lsim[2][32], lg2[2][32];

    u16* As_hi = (u16*)smemf;          // 1280 u16 (32 rows)
    u16* As_lo = As_hi + 1280;
    u16* Wst   = As_lo + 1280;         // per weight w: hi at w*5120, lo at +2560
    float* Qt = smemf;
    float* Kt = Qt + 32 * LDT;
    float* Vt = Kt + 32 * LDT;
    float* wkS = smemf + 6336;         // [2][1024], filled post-GEMM

    const int tid = threadIdx.x;
    const int mt = blockIdx.x, nt = blockIdx.y;
    const int m0 = mt * 32, ncol0 = nt * 64;
    const int bidx = m0 >> 11, lg = m0 & (Ls - 1);
    const int cg = lg >> 5;            // this block's chunk index
    const int wave = tid >> 6, lane = tid & 63;
    const int l15 = lane & 15, quad = lane >> 4;
    const int srow = tid >> 2, sk = (tid & 3) * 8;
    const int rf = wave & 1, cfp = wave >> 1;   // wave -> (row-frag, col-frag pair)

    const float* Wsrc[3] = {wq, wk, wv};
    f32x4 acc[3][2] = {};

    // -------- software-pipelined K loop (8 steps, fully unrolled) --------
    float4 ca0, ca1, cw0[3], cw1[3];
    if (tid < 128) {
        ca0 = *(const float4*)&x[(size_t)(m0 + srow) * 256 + 0 + sk];
        ca1 = *(const float4*)&x[(size_t)(m0 + srow) * 256 + 0 + sk + 4];
    }
#pragma unroll
    for (int w = 0; w < 3; ++w) {
        cw0[w] = *(const float4*)&Wsrc[w][(size_t)(ncol0 + srow) * 256 + 0 + sk];
        cw1[w] = *(const float4*)&Wsrc[w][(size_t)(ncol0 + srow) * 256 + 0 + sk + 4];
    }

#pragma unroll
    for (int kk = 0; kk < 8; ++kk) {
        __syncthreads();               // prev MFMA done reading staging
        {
            uint4 hi, lo;
            if (tid < 128) {
                split8(ca0, ca1, hi, lo);
                *(uint4*)&As_hi[srow * LDK + sk] = hi;
                *(uint4*)&As_lo[srow * LDK + sk] = lo;
            }
#pragma unroll
            for (int w = 0; w < 3; ++w) {
                split8(cw0[w], cw1[w], hi, lo);
                *(uint4*)&Wst[w * 5120 + srow * LDK + sk] = hi;
                *(uint4*)&Wst[w * 5120 + 2560 + srow * LDK + sk] = lo;
            }
        }
        __syncthreads();

        // issue next step's loads; latency hides under the MFMA phase below
        if (kk < 7) {
            const int k0n = (kk + 1) * 32;
            if (tid < 128) {
                ca0 = *(const float4*)&x[(size_t)(m0 + srow) * 256 + k0n + sk];
                ca1 = *(const float4*)&x[(size_t)(m0 + srow) * 256 + k0n + sk + 4];
            }
#pragma unroll
            for (int w = 0; w < 3; ++w) {
                cw0[w] = *(const float4*)&Wsrc[w][(size_t)(ncol0 + srow) * 256 + k0n + sk];
                cw1[w] = *(const float4*)&Wsrc[w][(size_t)(ncol0 + srow) * 256 + k0n + sk + 4];
            }
        }

        const frag ah = *(const frag*)&As_hi[(rf * 16 + l15) * LDK + quad * 8];
        const frag al = *(const frag*)&As_lo[(rf * 16 + l15) * LDK + quad * 8];
#pragma unroll
        for (int w = 0; w < 3; ++w)
#pragma unroll
            for (int cf = 0; cf < 2; ++cf) {
                const u16* bp = &Wst[w * 5120 + ((cfp * 2 + cf) * 16 + l15) * LDK + quad * 8];
                const frag bh = *(const frag*)bp;
                const frag bl = *(const frag*)(bp + 2560);
                acc[w][cf] = __builtin_amdgcn_mfma_f32_16x16x32_bf16(ah, bh, acc[w][cf], 0, 0, 0);
                acc[w][cf] = __builtin_amdgcn_mfma_f32_16x16x32_bf16(ah, bl, acc[w][cf], 0, 0, 0);
                acc[w][cf] = __builtin_amdgcn_mfma_f32_16x16x32_bf16(al, bh, acc[w][cf], 0, 0, 0);
            }
    }
    __syncthreads();   // staging dead; write tiles + wkS (aliased region)

    {
        float* tiles[3] = {Qt, Kt, Vt};
        const float* biases[3] = {bq, bk, bv};
#pragma unroll
        for (int w = 0; w < 3; ++w)
#pragma unroll
            for (int cf = 0; cf < 2; ++cf) {
                const int col = (cfp * 2 + cf) * 16 + l15;
                const float bias = biases[w][ncol0 + col];
#pragma unroll
                for (int r = 0; r < 4; ++r) {
                    const int m = rf * 16 + quad * 4 + r;
                    tiles[w][m * LDT + col] = acc[w][cf][r] + bias;
                }
            }
        // wg_w * kvs for this block's two heads (region disjoint from tiles)
        for (int i = tid; i < 2048; i += 256) {
            const int h = i >> 10, de = i & 1023;
            wkS[h * 1024 + de] = wg_w[de] * kvs[(nt * 2 + h) * 1024 + de];
        }
    }
    __syncthreads();

    // ---- Phase N: per (h,l) normalize k,v in place; sim. 4 threads/task ----
    {
        const int task = tid >> 2, sub = tid & 3;   // task = h*32 + l
        const int h = task >> 5, l = task & 31;
        const int cb = h * 32, e0 = sub * 8;
        float ksum = 0.f, vsum = 0.f, qk = 0.f;
#pragma unroll
        for (int e = e0; e < e0 + 8; ++e) {
            const float kv = Kt[l * LDT + cb + e];
            const float vv = Vt[l * LDT + cb + e];
            const float qv = Qt[l * LDT + cb + e];
            ksum = fmaf(kv, kv, ksum);
            vsum = fmaf(vv, vv, vsum);
            qk = fmaf(qv, kv, qk);
        }
        ksum += __shfl_xor(ksum, 1); ksum += __shfl_xor(ksum, 2);
        vsum += __shfl_xor(vsum, 1); vsum += __shfl_xor(vsum, 2);
        qk   += __shfl_xor(qk, 1);   qk   += __shfl_xor(qk, 2);
        const float kscale = 1.f / fmaxf(sqrtf(ksum), 1e-12f);
        const float vscale = 1.f / fmaxf(sqrtf(vsum), 1e-12f);
#pragma unroll
        for (int e = e0; e < e0 + 8; ++e) {
            Kt[l * LDT + cb + e] *= kscale;
            Vt[l * LDT + cb + e] *= vscale;
        }
        if (sub == 0) {
            const float sim = qk * qks[nt * 2 + h];
            lsim[h][l] = sim;
            simG[(size_t)(bidx * 8 + nt * 2 + h) * Ls + lg + l] = sim;
        }
    }
    __syncthreads();

    // ---- Phase copy: q, kn, vn to global (coalesced float2) ----
    {
        const float* tl[3] = {Qt, Kt, Vt};
        float* gl[3] = {qh, kh, vh};
#pragma unroll
        for (int arr = 0; arr < 3; ++arr)
#pragma unroll
            for (int it = 0; it < 4; ++it) {
                const int idx = it * 512 + tid * 2;      // 0..2046
                const int l = idx >> 6, col = idx & 63;
                const int h = col >> 5, e = col & 31;
                float2 v;
                v.x = tl[arr][l * LDT + h * 32 + e];
                v.y = tl[arr][l * LDT + h * 32 + e + 1];
                *(float2*)&gl[arr][(size_t)(bidx * 8 + nt * 2 + h) * 65536 +
                                   (size_t)(lg + l) * 32 + e] = v;
            }
    }

    // ---- Phase G: gate per (h,l); 4 threads per task ----
    {
        const int task = tid >> 2, sub = tid & 3;
        const int h = task >> 5, l = task & 31;
        float vreg[32];
#pragma unroll 8
        for (int d = 0; d < 32; ++d) vreg[d] = Vt[l * LDT + h * 32 + d];
        float u = 0.f;
        const int e0 = sub * 8;
#pragma unroll
        for (int e = e0; e < e0 + 8; ++e) {
            float s = 0.f;
#pragma unroll 8
            for (int d = 0; d < 32; ++d)
                s = fmaf(vreg[d], wkS[h * 1024 + d * 32 + e], s);
            u = fmaf(s, Kt[l * LDT + h * 32 + e], u);
        }
        u += __shfl_xor(u, 1);
        u += __shfl_xor(u, 2);
        if (sub == 0) {
            const float r = fmaxf(u + wg_b[0], 0.f);
            const float g = r * r + EPSV;
            lg2[h][l] = g;
            gG[(size_t)(bidx * 8 + nt * 2 + h) * Ls + lg + l] = g;
        }
    }
    __syncthreads();

    // ---- Phase Z: chunk-Z totals (2 heads, one 32-chunk) ----
    {
        const int d = tid >> 3, e0 = (tid & 7) * 4;
#pragma unroll
        for (int h = 0; h < 2; ++h) {
            float z0 = 0.f, z1 = 0.f, z2 = 0.f, z3 = 0.f;
#pragma unroll 8
            for (int l = 0; l < 32; ++l) {
                const float gv = lg2[h][l] * Vt[l * LDT + h * 32 + d];
                z0 = fmaf(gv, Kt[l * LDT + h * 32 + e0 + 0], z0);
                z1 = fmaf(gv, Kt[l * LDT + h * 32 + e0 + 1], z1);
                z2 = fmaf(gv, Kt[l * LDT + h * 32 + e0 + 2], z2);
                z3 = fmaf(gv, Kt[l * LDT + h * 32 + e0 + 3], z3);
            }
            const int bhg = bidx * 8 + nt * 2 + h;
            float4 zv; zv.x = z0; zv.y = z1; zv.z = z2; zv.w = z3;
            *(float4*)&ZcT[((size_t)bhg * NCH + cg) * 1024 + d * 32 + e0] = zv;
        }
    }

    // ---- (m,s,g) chunk totals: wave h in {0,1} handles head h ----
    if (wave < 2 && lane < 32) {
        const int h = wave;
        float m = lsim[h][lane], s = 1.f, g = lg2[h][lane];
#pragma unroll
        for (int off = 16; off; off >>= 1) {
            const float mo = __shfl_xor(m, off);
            const float so = __shfl_xor(s, off);
            const float mn = fmaxf(m, mo);
            s = s * __expf(m - mn) + so * __expf(mo - mn);
            m = mn;
            g += __shfl_xor(g, off);
        }
        if (lane == 0) {
            const int bhg = bidx * 8 + nt * 2 + h;
            mT[bhg * NCH + cg] = m;
            sT[bhg * NCH + cg] = s;
            gTt[bhg * NCH + cg] = g;
        }
    }
}

// ---------------- prefix: exclusive prefixes over chunks + rank-1 setup ----------
__global__ __launch_bounds__(256) void prefix_kernel(
    float* __restrict__ Zc, float* __restrict__ mT, float* __restrict__ sT,
    float* __restrict__ gTt,
    const float* __restrict__ kvs, float* __restrict__ aW, float* __restrict__ bW,
    int* __restrict__ flagW)
{
    const int bh = blockIdx.x, seg = blockIdx.y;
    const int tid = threadIdx.x;
    const int el = seg * 256 + tid;
    float* Zb = Zc + (size_t)bh * NCH * 1024 + el;

    float v[NCH];
#pragma unroll
    for (int i = 0; i < NCH; ++i) v[i] = Zb[(size_t)i * 1024];
    float run = 0.f;
#pragma unroll
    for (int i = 0; i < NCH; ++i) {
        const float t = v[i];
        Zb[(size_t)i * 1024] = run;
        run += t;
    }

    if (seg == 0 && tid < 64) {
        float m = mT[bh * NCH + tid], s = sT[bh * NCH + tid], g = gTt[bh * NCH + tid];
#pragma unroll
        for (int off = 1; off < 64; off <<= 1) {
            const float mo = __shfl_up(m, off);
            const float so = __shfl_up(s, off);
            const float go = __shfl_up(g, off);
            if (tid >= off) {
                const float mn = fmaxf(m, mo);
                s = s * __expf(m - mn) + so * __expf(mo - mn);
                m = mn;
                g += go;
            }
        }
        float me = __shfl_up(m, 1), se = __shfl_up(s, 1), ge = __shfl_up(g, 1);
        if (tid == 0) { me = -1e30f; se = 0.f; ge = 0.f; }
        mT[bh * NCH + tid] = me;
        sT[bh * NCH + tid] = se;
        gTt[bh * NCH + tid] = ge;
    }

    if (bh == 0 && seg == 3) {
        const int h = tid >> 5, e = tid & 31;
        const float* K = kvs + h * 1024;
        const float k00 = K[0];
        int ok = (k00 != 0.0f);
        for (int d = 0; d < 32; ++d) {
            const float lhs = K[d * 32 + e] * k00;
            const float rhs = K[d * 32] * K[e];
            const float diff = fabsf(lhs - rhs);
            if (diff > 1e-6f * fmaxf(fmaxf(fabsf(lhs), fabsf(rhs)), 1e-20f)) ok = 0;
        }
        aW[h * 32 + e] = K[e * 32];
        bW[h * 32 + e] = (k00 != 0.0f) ? K[e] / k00 : 0.f;
        const int allok = __syncthreads_and(ok);
        if (tid == 0) flagW[0] = allok;
    }
}

// ---------------- chunk_out: matmul-shaped replay, emit ctxt as hi/lo bf16 ----------
// __launch_bounds__(1024, 8): guarantee 2 blocks/CU (VGPR <= 64).
__global__ __launch_bounds__(1024, 8) void chunk_out_kernel(
    const float* __restrict__ qh, const float* __restrict__ knG, const float* __restrict__ vnG,
    const float* __restrict__ simG, const float* __restrict__ gG,
    const float* __restrict__ kvs,
    const float* __restrict__ ZcP, const float* __restrict__ mP,
    const float* __restrict__ sP, const float* __restrict__ gP,
    const float* __restrict__ aW, const float* __restrict__ bW,
    const int* __restrict__ flagW,
    u16* __restrict__ chi, u16* __restrict__ clo)
{
    __shared__ float qa[1024], knb[1024], zp[1024], lkvs[1024];
    __shared__ float vnT[32 * 33], sW[32 * 33];
    __shared__ float la[32], lb[32], lg[T], lsim[T], lwgt[T];
    const int tid = threadIdx.x;
    const int c = blockIdx.x, bh = blockIdx.y, h = bh & 7, b = bh >> 3;
    const int l = tid >> 5, lane = tid & 31;
    const size_t base = ((size_t)bh * Ls + c * T) * 32;

    // all loads issued up front, unconditionally (no flag-dependent load chain)
    const float qv = qh[base + tid];
    const float knv = knG[base + tid];
    const float vnv = vnG[base + tid];
    const float kvsv = kvs[h * 1024 + tid];
    const int flag = flagW[0];
    vnT[lane * 33 + l] = vnv;
    zp[tid] = ZcP[((size_t)bh * NCH + c) * 1024 + tid];
    lkvs[tid] = kvsv;
    if (tid < 32) {
        la[tid] = aW[h * 32 + tid];
        lb[tid] = bW[h * 32 + tid];
        lg[tid] = gG[bh * Ls + c * T + tid];
        lsim[tid] = simG[bh * Ls + c * T + tid];
    }
    __syncthreads();

    qa[tid] = flag ? qv * la[lane] : qv;
    knb[tid] = flag ? knv * lb[lane] : knv;
    if (tid < 32) {
        float m = lsim[tid], s = 1.f, g = lg[tid];
#pragma unroll
        for (int off = 1; off < 32; off <<= 1) {
            const float mo = __shfl_up(m, off);
            const float so = __shfl_up(s, off);
            const float go = __shfl_up(g, off);
            if (tid >= off) {
                const float mn = fmaxf(m, mo);
                s = s * __expf(m - mn) + so * __expf(mo - mn);
                m = mn;
                g += go;
            }
        }
        const float mp = mP[bh * NCH + c];
        const float sp = sP[bh * NCH + c];
        const float gp = gP[bh * NCH + c];
        const float mn = fmaxf(mp, m);
        s = sp * __expf(mp - mn) + s * __expf(m - mn);
        m = mn;
        g += gp;
        const float sw = __expf(lsim[tid] - m) / (s + EPSV);
        const float sig = 1.f / (1.f + __expf(-sw));
        lwgt[tid] = (1.f + sw * sig) / (g + EPSV);
    }
    __syncthreads();

    float y;
    if (flag) {
        float s = 0.f, y0 = 0.f;
        const float4* qa4 = (const float4*)&qa[l * 32];
#pragma unroll
        for (int d4 = 0; d4 < 8; ++d4) {
            const float4 q4 = qa4[d4];
            const int d = d4 * 4;
            s = fmaf(q4.x, vnT[(d + 0) * 33 + lane], s);
            s = fmaf(q4.y, vnT[(d + 1) * 33 + lane], s);
            s = fmaf(q4.z, vnT[(d + 2) * 33 + lane], s);
            s = fmaf(q4.w, vnT[(d + 3) * 33 + lane], s);
            y0 = fmaf(q4.x, zp[(d + 0) * 32 + lane], y0);
            y0 = fmaf(q4.y, zp[(d + 1) * 32 + lane], y0);
            y0 = fmaf(q4.z, zp[(d + 2) * 32 + lane], y0);
            y0 = fmaf(q4.w, zp[(d + 3) * 32 + lane], y0);
        }
        sW[l * 33 + lane] = (lane <= l) ? lg[lane] * s : 0.f;
        __syncthreads();
        y = y0 * lb[lane];
#pragma unroll 8
        for (int j = 0; j < 32; ++j)
            y = fmaf(sW[l * 33 + j], knb[j * 32 + lane], y);
        y *= lwgt[l];
    } else {
        float qe[32];
#pragma unroll
        for (int d = 0; d < 32; ++d)
            qe[d] = qa[l * 32 + d] * lkvs[d * 32 + lane];
        y = 0.f;
#pragma unroll
        for (int d = 0; d < 32; ++d)
            y = fmaf(qe[d], zp[d * 32 + lane], y);
        for (int j = 0; j < 32; ++j) {
            float s = 0.f;
#pragma unroll
            for (int d = 0; d < 32; ++d)
                s = fmaf(qe[d], vnT[d * 33 + j], s);
            if (j <= l) y = fmaf(lg[j] * s, knb[j * 32 + lane], y);
        }
        y *= lwgt[l];
    }
    u16 hi, lo;
    split_bf16(y, hi, lo);
    const size_t oidx = ((size_t)(b * Ls + c * T + l)) * 256 + h * 32 + lane;
    chi[oidx] = hi;
    clo[oidx] = lo;
}

// ---------------- out_gemm: 32x32-tile split-bf16 MFMA, W split on the fly ----------
// Tile shrunk 32x64 -> 32x32: grid (128,8) = 1024 blocks = 4 blocks/CU
// (was 512 = 2/CU, grid-limited occupancy). Register-prefetch pipelined.
__global__ __launch_bounds__(256) void out_gemm(
    const u16* __restrict__ Ahi, const u16* __restrict__ Alo,
    const float* __restrict__ wo, const float* __restrict__ bo,
    float* __restrict__ out)
{
    constexpr int LDK = 40;
    __shared__ __align__(16) u16 As_hi[32 * LDK];
    __shared__ __align__(16) u16 As_lo[32 * LDK];
    __shared__ __align__(16) u16 Ws_hi[32 * LDK];
    __shared__ __align__(16) u16 Ws_lo[32 * LDK];

    const int tid = threadIdx.x;
    const int mt = blockIdx.x, nt = blockIdx.y;
    const int m0 = mt * 32, ncol0 = nt * 32;
    const int wave = tid >> 6, lane = tid & 63;
    const int l15 = lane & 15, quad = lane >> 4;
    const int srow = tid >> 2, sk = (tid & 3) * 8;   // srow 0..63: 0-31 A, 32-63 W
    const int rf = wave & 1, cf = wave >> 1;         // 2x2 of 16x16 frags

    f32x4 acc = {};

    uint4 cah, cal;
    float4 cw0, cw1;
    if (tid < 128) {
        cah = *(const uint4*)&Ahi[(size_t)(m0 + srow) * 256 + 0 + sk];
        cal = *(const uint4*)&Alo[(size_t)(m0 + srow) * 256 + 0 + sk];
    } else {
        cw0 = *(const float4*)&wo[(size_t)(ncol0 + srow - 32) * 256 + 0 + sk];
        cw1 = *(const float4*)&wo[(size_t)(ncol0 + srow - 32) * 256 + 0 + sk + 4];
    }

#pragma unroll
    for (int kk = 0; kk < 8; ++kk) {
        __syncthreads();
        if (tid < 128) {
            *(uint4*)&As_hi[srow * LDK + sk] = cah;
            *(uint4*)&As_lo[srow * LDK + sk] = cal;
        } else {
            uint4 whi, wlo;
            split8(cw0, cw1, whi, wlo);
            *(uint4*)&Ws_hi[(srow - 32) * LDK + sk] = whi;
            *(uint4*)&Ws_lo[(srow - 32) * LDK + sk] = wlo;
        }
        __syncthreads();

        if (kk < 7) {
            const int k0n = (kk + 1) * 32;
            if (tid < 128) {
                cah = *(const uint4*)&Ahi[(size_t)(m0 + srow) * 256 + k0n + sk];
                cal = *(const uint4*)&Alo[(size_t)(m0 + srow) * 256 + k0n + sk];
            } else {
                cw0 = *(const float4*)&wo[(size_t)(ncol0 + srow - 32) * 256 + k0n + sk];
                cw1 = *(const float4*)&wo[(size_t)(ncol0 + srow - 32) * 256 + k0n + sk + 4];
            }
        }

        const frag fah = *(const frag*)&As_hi[(rf * 16 + l15) * LDK + quad * 8];
        const frag fal = *(const frag*)&As_lo[(rf * 16 + l15) * LDK + quad * 8];
        const frag fbh = *(const frag*)&Ws_hi[(cf * 16 + l15) * LDK + quad * 8];
        const frag fbl = *(const frag*)&Ws_lo[(cf * 16 + l15) * LDK + quad * 8];
        acc = __builtin_amdgcn_mfma_f32_16x16x32_bf16(fah, fbh, acc, 0, 0, 0);
        acc = __builtin_amdgcn_mfma_f32_16x16x32_bf16(fah, fbl, acc, 0, 0, 0);
        acc = __builtin_amdgcn_mfma_f32_16x16x32_bf16(fal, fbh, acc, 0, 0, 0);
    }

    {
        const int o = ncol0 + cf * 16 + l15;
        const float bias = bo[o];
#pragma unroll
        for (int r = 0; r < 4; ++r) {
            const int rm = m0 + rf * 16 + quad * 4 + r;
            out[(size_t)rm * 256 + o] = acc[r] + bias;
        }
    }
}

extern "C" void kernel_launch(void* const* d_in, const int* in_sizes, int n_in,
                              void* d_out, int out_size, void* d_ws, size_t ws_size,
                              hipStream_t stream) {
    const float* x    = (const float*)d_in[0];
    const float* wq_w = (const float*)d_in[1];
    const float* wq_b = (const float*)d_in[2];
    const float* wk_w = (const float*)d_in[3];
    const float* wk_b = (const float*)d_in[4];
    const float* wv_w = (const float*)d_in[5];
    const float* wv_b = (const float*)d_in[6];
    const float* wo_w = (const float*)d_in[7];
    const float* wo_b = (const float*)d_in[8];
    const float* wg_w = (const float*)d_in[9];
    const float* wg_b = (const float*)d_in[10];
    const float* kvs  = (const float*)d_in[11];
    const float* qks  = (const float*)d_in[12];
    float* out = (float*)d_out;

    u16* chi = (u16*)d_ws;                 // 1048576 u16
    u16* clo = chi + 1048576;              // 1048576 u16
    float* qh   = (float*)(clo + 1048576); // 1048576 f32
    float* kh   = qh + 1048576;
    float* vh   = kh + 1048576;
    float* ZcT  = vh + 1048576;            // 1048576
    float* simG = ZcT + 1048576;           // 32768
    float* gG   = simG + 32768;            // 32768
    float* mT   = gG + 32768;              // 1024
    float* sT   = mT + 1024;
    float* gTt  = sT + 1024;
    float* aW   = gTt + 1024;              // 256
    float* bW   = aW + 256;                // 256
    int* flagW  = (int*)(bW + 256);
    // total ~20.5 MB

    qkv_fused<<<dim3(128, 4), 256, 0, stream>>>(
        x, wq_w, wk_w, wv_w, wq_b, wk_b, wv_b, wg_w, wg_b, kvs, qks,
        qh, kh, vh, simG, gG, ZcT, mT, sT, gTt);
    prefix_kernel<<<dim3(16, 4), 256, 0, stream>>>(
        ZcT, mT, sT, gTt, kvs, aW, bW, flagW);
    chunk_out_kernel<<<dim3(NCH, 16), 1024, 0, stream>>>(
        qh, kh, vh, simG, gG, kvs, ZcT, mT, sT, gTt, aW, bW, flagW, chi, clo);
    out_gemm<<<dim3(128, 8), 256, 0, stream>>>(
        chi, clo, wo_w, wo_b, out);
}

// Round 4
// 131.921 us; speedup vs baseline: 1.2147x; 1.2147x over previous
//
#include <hip/hip_runtime.h>
#include <math.h>

#define EPSV 1e-5f

static constexpr int Ls = 2048, Hh = 8;
static constexpr int NCH = 64, T = 32;   // 64 chunks of 32 along L

typedef unsigned short u16;
using frag  = __attribute__((ext_vector_type(8))) short;   // 8 x bf16 (4 VGPRs)
using f32x4 = __attribute__((ext_vector_type(4))) float;

__device__ __forceinline__ void split_bf16(float v, u16& hi, u16& lo) {
    const unsigned u = __float_as_uint(v);
    hi = (u16)(u >> 16);
    const float hf = __uint_as_float((unsigned)hi << 16);
    lo = (u16)(__float_as_uint(v - hf) >> 16);
}

__device__ __forceinline__ unsigned pk2(u16 a, u16 b) {
    return (unsigned)a | ((unsigned)b << 16);
}

// split 8 fp32 into one uint4 of hi-bf16 and one uint4 of lo-bf16
__device__ __forceinline__ void split8(const float4& a, const float4& b,
                                       uint4& hi, uint4& lo) {
    u16 h[8], l[8];
    const float f[8] = {a.x, a.y, a.z, a.w, b.x, b.y, b.z, b.w};
#pragma unroll
    for (int i = 0; i < 8; ++i) split_bf16(f[i], h[i], l[i]);
    hi = make_uint4(pk2(h[0], h[1]), pk2(h[2], h[3]), pk2(h[4], h[5]), pk2(h[6], h[7]));
    lo = make_uint4(pk2(l[0], l[1]), pk2(l[2], l[3]), pk2(l[4], l[5]), pk2(l[6], l[7]));
}

// =====================================================================
// qkv_fused: split-bf16 MFMA GEMM for q,k,v (32 rows x 2 heads per block)
// + fused chunk_sum epilogue (normalize, sim, gate, chunk-Z, (m,s,g) totals)
// grid: (128 row-tiles, 4 head-pairs) x 256 threads (4 waves).
// LDS ~36.4 KB (wkS aliased into smemf, filled post-GEMM) -> up to 4
// blocks/CU by LDS. NO min-waves launch bound: forcing the allocator caused
// spills in round 3; occupancy is controlled via LDS/grid only.
// =====================================================================
__global__ __launch_bounds__(256) void qkv_fused(
    const float* __restrict__ x,
    const float* __restrict__ wq, const float* __restrict__ wk, const float* __restrict__ wv,
    const float* __restrict__ bq, const float* __restrict__ bk, const float* __restrict__ bv,
    const float* __restrict__ wg_w, const float* __restrict__ wg_b,
    const float* __restrict__ kvs, const float* __restrict__ qks,
    float* __restrict__ qh, float* __restrict__ kh, float* __restrict__ vh,
    float* __restrict__ simG, float* __restrict__ gG,
    float* __restrict__ ZcT, float* __restrict__ mT, float* __restrict__ sT,
    float* __restrict__ gTt)
{
    constexpr int LDK = 40;     // u16 per staged row (80 B, 16B-aligned)
    constexpr int LDT = 66;     // f32 per tile row (264 B: 8B-aligned, 2-way banks)
    // one region, overlapping uses separated by barriers:
    //   staging (35840 B) during GEMM; tiles (25344 B = f32[0,6336)) +
    //   wkS (8192 B = f32[6336,8384)) after GEMM.
    __shared__ __align__(16) float smemf[8960];
    __shared__ float lsim[2][32], lg2[2][32];

    u16* As_hi = (u16*)smemf;          // 1280 u16 (32 rows)
    u16* As_lo = As_hi + 1280;
    u16* Wst   = As_lo + 1280;         // per weight w: hi at w*5120, lo at +2560
    float* Qt = smemf;
    float* Kt = Qt + 32 * LDT;
    float* Vt = Kt + 32 * LDT;
    float* wkS = smemf + 6336;         // [2][1024], filled post-GEMM

    const int tid = threadIdx.x;
    const int mt = blockIdx.x, nt = blockIdx.y;
    const int m0 = mt * 32, ncol0 = nt * 64;
    const int bidx = m0 >> 11, lg = m0 & (Ls - 1);
    const int cg = lg >> 5;            // this block's chunk index
    const int wave = tid >> 6, lane = tid & 63;
    const int l15 = lane & 15, quad = lane >> 4;
    const int srow = tid >> 2, sk = (tid & 3) * 8;
    const int rf = wave & 1, cfp = wave >> 1;   // wave -> (row-frag, col-frag pair)

    const float* Wsrc[3] = {wq, wk, wv};
    f32x4 acc[3][2] = {};

    // -------- software-pipelined K loop (8 steps, fully unrolled) --------
    float4 ca0, ca1, cw0[3], cw1[3];
    if (tid < 128) {
        ca0 = *(const float4*)&x[(size_t)(m0 + srow) * 256 + 0 + sk];
        ca1 = *(const float4*)&x[(size_t)(m0 + srow) * 256 + 0 + sk + 4];
    }
#pragma unroll
    for (int w = 0; w < 3; ++w) {
        cw0[w] = *(const float4*)&Wsrc[w][(size_t)(ncol0 + srow) * 256 + 0 + sk];
        cw1[w] = *(const float4*)&Wsrc[w][(size_t)(ncol0 + srow) * 256 + 0 + sk + 4];
    }

#pragma unroll
    for (int kk = 0; kk < 8; ++kk) {
        __syncthreads();               // prev MFMA done reading staging
        {
            uint4 hi, lo;
            if (tid < 128) {
                split8(ca0, ca1, hi, lo);
                *(uint4*)&As_hi[srow * LDK + sk] = hi;
                *(uint4*)&As_lo[srow * LDK + sk] = lo;
            }
#pragma unroll
            for (int w = 0; w < 3; ++w) {
                split8(cw0[w], cw1[w], hi, lo);
                *(uint4*)&Wst[w * 5120 + srow * LDK + sk] = hi;
                *(uint4*)&Wst[w * 5120 + 2560 + srow * LDK + sk] = lo;
            }
        }
        __syncthreads();

        // issue next step's loads; latency hides under the MFMA phase below
        if (kk < 7) {
            const int k0n = (kk + 1) * 32;
            if (tid < 128) {
                ca0 = *(const float4*)&x[(size_t)(m0 + srow) * 256 + k0n + sk];
                ca1 = *(const float4*)&x[(size_t)(m0 + srow) * 256 + k0n + sk + 4];
            }
#pragma unroll
            for (int w = 0; w < 3; ++w) {
                cw0[w] = *(const float4*)&Wsrc[w][(size_t)(ncol0 + srow) * 256 + k0n + sk];
                cw1[w] = *(const float4*)&Wsrc[w][(size_t)(ncol0 + srow) * 256 + k0n + sk + 4];
            }
        }

        const frag ah = *(const frag*)&As_hi[(rf * 16 + l15) * LDK + quad * 8];
        const frag al = *(const frag*)&As_lo[(rf * 16 + l15) * LDK + quad * 8];
#pragma unroll
        for (int w = 0; w < 3; ++w)
#pragma unroll
            for (int cf = 0; cf < 2; ++cf) {
                const u16* bp = &Wst[w * 5120 + ((cfp * 2 + cf) * 16 + l15) * LDK + quad * 8];
                const frag bh = *(const frag*)bp;
                const frag bl = *(const frag*)(bp + 2560);
                acc[w][cf] = __builtin_amdgcn_mfma_f32_16x16x32_bf16(ah, bh, acc[w][cf], 0, 0, 0);
                acc[w][cf] = __builtin_amdgcn_mfma_f32_16x16x32_bf16(ah, bl, acc[w][cf], 0, 0, 0);
                acc[w][cf] = __builtin_amdgcn_mfma_f32_16x16x32_bf16(al, bh, acc[w][cf], 0, 0, 0);
            }
    }
    __syncthreads();   // staging dead; write tiles + wkS (aliased region)

    {
        float* tiles[3] = {Qt, Kt, Vt};
        const float* biases[3] = {bq, bk, bv};
#pragma unroll
        for (int w = 0; w < 3; ++w)
#pragma unroll
            for (int cf = 0; cf < 2; ++cf) {
                const int col = (cfp * 2 + cf) * 16 + l15;
                const float bias = biases[w][ncol0 + col];
#pragma unroll
                for (int r = 0; r < 4; ++r) {
                    const int m = rf * 16 + quad * 4 + r;
                    tiles[w][m * LDT + col] = acc[w][cf][r] + bias;
                }
            }
        // wg_w * kvs for this block's two heads (region disjoint from tiles)
        for (int i = tid; i < 2048; i += 256) {
            const int h = i >> 10, de = i & 1023;
            wkS[h * 1024 + de] = wg_w[de] * kvs[(nt * 2 + h) * 1024 + de];
        }
    }
    __syncthreads();

    // ---- Phase N: per (h,l) normalize k,v in place; sim. 4 threads/task ----
    {
        const int task = tid >> 2, sub = tid & 3;   // task = h*32 + l
        const int h = task >> 5, l = task & 31;
        const int cb = h * 32, e0 = sub * 8;
        float ksum = 0.f, vsum = 0.f, qk = 0.f;
#pragma unroll
        for (int e = e0; e < e0 + 8; ++e) {
            const float kv = Kt[l * LDT + cb + e];
            const float vv = Vt[l * LDT + cb + e];
            const float qv = Qt[l * LDT + cb + e];
            ksum = fmaf(kv, kv, ksum);
            vsum = fmaf(vv, vv, vsum);
            qk = fmaf(qv, kv, qk);
        }
        ksum += __shfl_xor(ksum, 1); ksum += __shfl_xor(ksum, 2);
        vsum += __shfl_xor(vsum, 1); vsum += __shfl_xor(vsum, 2);
        qk   += __shfl_xor(qk, 1);   qk   += __shfl_xor(qk, 2);
        const float kscale = 1.f / fmaxf(sqrtf(ksum), 1e-12f);
        const float vscale = 1.f / fmaxf(sqrtf(vsum), 1e-12f);
#pragma unroll
        for (int e = e0; e < e0 + 8; ++e) {
            Kt[l * LDT + cb + e] *= kscale;
            Vt[l * LDT + cb + e] *= vscale;
        }
        if (sub == 0) {
            const float sim = qk * qks[nt * 2 + h];
            lsim[h][l] = sim;
            simG[(size_t)(bidx * 8 + nt * 2 + h) * Ls + lg + l] = sim;
        }
    }
    __syncthreads();

    // ---- Phase copy: q, kn, vn to global (coalesced float2) ----
    {
        const float* tl[3] = {Qt, Kt, Vt};
        float* gl[3] = {qh, kh, vh};
#pragma unroll
        for (int arr = 0; arr < 3; ++arr)
#pragma unroll
            for (int it = 0; it < 4; ++it) {
                const int idx = it * 512 + tid * 2;      // 0..2046
                const int l = idx >> 6, col = idx & 63;
                const int h = col >> 5, e = col & 31;
                float2 v;
                v.x = tl[arr][l * LDT + h * 32 + e];
                v.y = tl[arr][l * LDT + h * 32 + e + 1];
                *(float2*)&gl[arr][(size_t)(bidx * 8 + nt * 2 + h) * 65536 +
                                   (size_t)(lg + l) * 32 + e] = v;
            }
    }

    // ---- Phase G: gate per (h,l); 4 threads per task ----
    {
        const int task = tid >> 2, sub = tid & 3;
        const int h = task >> 5, l = task & 31;
        float vreg[32];
#pragma unroll 8
        for (int d = 0; d < 32; ++d) vreg[d] = Vt[l * LDT + h * 32 + d];
        float u = 0.f;
        const int e0 = sub * 8;
#pragma unroll
        for (int e = e0; e < e0 + 8; ++e) {
            float s = 0.f;
#pragma unroll 8
            for (int d = 0; d < 32; ++d)
                s = fmaf(vreg[d], wkS[h * 1024 + d * 32 + e], s);
            u = fmaf(s, Kt[l * LDT + h * 32 + e], u);
        }
        u += __shfl_xor(u, 1);
        u += __shfl_xor(u, 2);
        if (sub == 0) {
            const float r = fmaxf(u + wg_b[0], 0.f);
            const float g = r * r + EPSV;
            lg2[h][l] = g;
            gG[(size_t)(bidx * 8 + nt * 2 + h) * Ls + lg + l] = g;
        }
    }
    __syncthreads();

    // ---- Phase Z: chunk-Z totals (2 heads, one 32-chunk) ----
    {
        const int d = tid >> 3, e0 = (tid & 7) * 4;
#pragma unroll
        for (int h = 0; h < 2; ++h) {
            float z0 = 0.f, z1 = 0.f, z2 = 0.f, z3 = 0.f;
#pragma unroll 8
            for (int l = 0; l < 32; ++l) {
                const float gv = lg2[h][l] * Vt[l * LDT + h * 32 + d];
                z0 = fmaf(gv, Kt[l * LDT + h * 32 + e0 + 0], z0);
                z1 = fmaf(gv, Kt[l * LDT + h * 32 + e0 + 1], z1);
                z2 = fmaf(gv, Kt[l * LDT + h * 32 + e0 + 2], z2);
                z3 = fmaf(gv, Kt[l * LDT + h * 32 + e0 + 3], z3);
            }
            const int bhg = bidx * 8 + nt * 2 + h;
            float4 zv; zv.x = z0; zv.y = z1; zv.z = z2; zv.w = z3;
            *(float4*)&ZcT[((size_t)bhg * NCH + cg) * 1024 + d * 32 + e0] = zv;
        }
    }

    // ---- (m,s,g) chunk totals: wave h in {0,1} handles head h ----
    if (wave < 2 && lane < 32) {
        const int h = wave;
        float m = lsim[h][lane], s = 1.f, g = lg2[h][lane];
#pragma unroll
        for (int off = 16; off; off >>= 1) {
            const float mo = __shfl_xor(m, off);
            const float so = __shfl_xor(s, off);
            const float mn = fmaxf(m, mo);
            s = s * __expf(m - mn) + so * __expf(mo - mn);
            m = mn;
            g += __shfl_xor(g, off);
        }
        if (lane == 0) {
            const int bhg = bidx * 8 + nt * 2 + h;
            mT[bhg * NCH + cg] = m;
            sT[bhg * NCH + cg] = s;
            gTt[bhg * NCH + cg] = g;
        }
    }
}

// ---------------- prefix: exclusive prefixes over chunks + rank-1 setup ----------
__global__ __launch_bounds__(256) void prefix_kernel(
    float* __restrict__ Zc, float* __restrict__ mT, float* __restrict__ sT,
    float* __restrict__ gTt,
    const float* __restrict__ kvs, float* __restrict__ aW, float* __restrict__ bW,
    int* __restrict__ flagW)
{
    const int bh = blockIdx.x, seg = blockIdx.y;
    const int tid = threadIdx.x;
    const int el = seg * 256 + tid;
    float* Zb = Zc + (size_t)bh * NCH * 1024 + el;

    float v[NCH];
#pragma unroll
    for (int i = 0; i < NCH; ++i) v[i] = Zb[(size_t)i * 1024];
    float run = 0.f;
#pragma unroll
    for (int i = 0; i < NCH; ++i) {
        const float t = v[i];
        Zb[(size_t)i * 1024] = run;
        run += t;
    }

    if (seg == 0 && tid < 64) {
        float m = mT[bh * NCH + tid], s = sT[bh * NCH + tid], g = gTt[bh * NCH + tid];
#pragma unroll
        for (int off = 1; off < 64; off <<= 1) {
            const float mo = __shfl_up(m, off);
            const float so = __shfl_up(s, off);
            const float go = __shfl_up(g, off);
            if (tid >= off) {
                const float mn = fmaxf(m, mo);
                s = s * __expf(m - mn) + so * __expf(mo - mn);
                m = mn;
                g += go;
            }
        }
        float me = __shfl_up(m, 1), se = __shfl_up(s, 1), ge = __shfl_up(g, 1);
        if (tid == 0) { me = -1e30f; se = 0.f; ge = 0.f; }
        mT[bh * NCH + tid] = me;
        sT[bh * NCH + tid] = se;
        gTt[bh * NCH + tid] = ge;
    }

    if (bh == 0 && seg == 3) {
        const int h = tid >> 5, e = tid & 31;
        const float* K = kvs + h * 1024;
        const float k00 = K[0];
        int ok = (k00 != 0.0f);
        for (int d = 0; d < 32; ++d) {
            const float lhs = K[d * 32 + e] * k00;
            const float rhs = K[d * 32] * K[e];
            const float diff = fabsf(lhs - rhs);
            if (diff > 1e-6f * fmaxf(fmaxf(fabsf(lhs), fabsf(rhs)), 1e-20f)) ok = 0;
        }
        aW[h * 32 + e] = K[e * 32];
        bW[h * 32 + e] = (k00 != 0.0f) ? K[e] / k00 : 0.f;
        const int allok = __syncthreads_and(ok);
        if (tid == 0) flagW[0] = allok;
    }
}

// ---------------- chunk_out: matmul-shaped replay, emit ctxt as hi/lo bf16 ----------
// Plain __launch_bounds__(1024): round 3's (1024,8) forced VGPR=32 and ~120 MB
// of spill traffic per dispatch (FETCH 58 MB / WRITE 82 MB vs ~21 MB real).
// Serial tid<32 online-softmax scan replaced by a per-row parallel masked
// __shfl_xor reduction: all 32 row-groups reduce simultaneously, weight stays
// in a register (no lwgt LDS, no one-warp-runs-15-wait stall).
__global__ __launch_bounds__(1024) void chunk_out_kernel(
    const float* __restrict__ qh, const float* __restrict__ knG, const float* __restrict__ vnG,
    const float* __restrict__ simG, const float* __restrict__ gG,
    const float* __restrict__ kvs,
    const float* __restrict__ ZcP, const float* __restrict__ mP,
    const float* __restrict__ sP, const float* __restrict__ gP,
    const float* __restrict__ aW, const float* __restrict__ bW,
    const int* __restrict__ flagW,
    u16* __restrict__ chi, u16* __restrict__ clo)
{
    __shared__ float qa[1024], knb[1024], zp[1024], lkvs[1024];
    __shared__ float vnT[32 * 33], sW[32 * 33];
    __shared__ float la[32], lb[32], lg[T], lsim[T];
    const int tid = threadIdx.x;
    const int c = blockIdx.x, bh = blockIdx.y, h = bh & 7, b = bh >> 3;
    const int l = tid >> 5, lane = tid & 31;
    const size_t base = ((size_t)bh * Ls + c * T) * 32;

    // all loads issued up front, unconditionally (no flag-dependent load chain)
    const float qv = qh[base + tid];
    const float knv = knG[base + tid];
    const float vnv = vnG[base + tid];
    const float kvsv = kvs[h * 1024 + tid];
    const int flag = flagW[0];
    const float mp = mP[bh * NCH + c];     // scalar broadcast loads
    const float sp = sP[bh * NCH + c];
    const float gp = gP[bh * NCH + c];
    vnT[lane * 33 + l] = vnv;
    zp[tid] = ZcP[((size_t)bh * NCH + c) * 1024 + tid];
    lkvs[tid] = kvsv;
    if (tid < 32) {
        la[tid] = aW[h * 32 + tid];
        lb[tid] = bW[h * 32 + tid];
        lg[tid] = gG[bh * Ls + c * T + tid];
        lsim[tid] = simG[bh * Ls + c * T + tid];
    }
    __syncthreads();

    qa[tid] = flag ? qv * la[lane] : qv;
    knb[tid] = flag ? knv * lb[lane] : knv;

    // per-row parallel inclusive prefix (masked xor-reduce over the 32-lane
    // row group; identity for lanes > l). All rows compute concurrently.
    float wgt;
    {
        float mm = (lane <= l) ? lsim[lane] : -1e30f;
        float ss = (lane <= l) ? 1.f : 0.f;
        float gg = (lane <= l) ? lg[lane] : 0.f;
#pragma unroll
        for (int off = 1; off < 32; off <<= 1) {
            const float mo = __shfl_xor(mm, off);
            const float so = __shfl_xor(ss, off);
            const float go = __shfl_xor(gg, off);
            const float mn = fmaxf(mm, mo);
            ss = ss * __expf(mm - mn) + so * __expf(mo - mn);
            mm = mn;
            gg += go;
        }
        const float mn = fmaxf(mp, mm);
        const float s = sp * __expf(mp - mn) + ss * __expf(mm - mn);
        const float g = gg + gp;
        const float sw = __expf(lsim[l] - mn) / (s + EPSV);
        const float sig = 1.f / (1.f + __expf(-sw));
        wgt = (1.f + sw * sig) / (g + EPSV);
    }
    __syncthreads();

    float y;
    if (flag) {
        float s = 0.f, y0 = 0.f;
        const float4* qa4 = (const float4*)&qa[l * 32];
#pragma unroll
        for (int d4 = 0; d4 < 8; ++d4) {
            const float4 q4 = qa4[d4];
            const int d = d4 * 4;
            s = fmaf(q4.x, vnT[(d + 0) * 33 + lane], s);
            s = fmaf(q4.y, vnT[(d + 1) * 33 + lane], s);
            s = fmaf(q4.z, vnT[(d + 2) * 33 + lane], s);
            s = fmaf(q4.w, vnT[(d + 3) * 33 + lane], s);
            y0 = fmaf(q4.x, zp[(d + 0) * 32 + lane], y0);
            y0 = fmaf(q4.y, zp[(d + 1) * 32 + lane], y0);
            y0 = fmaf(q4.z, zp[(d + 2) * 32 + lane], y0);
            y0 = fmaf(q4.w, zp[(d + 3) * 32 + lane], y0);
        }
        sW[l * 33 + lane] = (lane <= l) ? lg[lane] * s : 0.f;
        __syncthreads();
        y = y0 * lb[lane];
#pragma unroll 8
        for (int j = 0; j < 32; ++j)
            y = fmaf(sW[l * 33 + j], knb[j * 32 + lane], y);
        y *= wgt;
    } else {
        float qe[32];
#pragma unroll
        for (int d = 0; d < 32; ++d)
            qe[d] = qa[l * 32 + d] * lkvs[d * 32 + lane];
        y = 0.f;
#pragma unroll
        for (int d = 0; d < 32; ++d)
            y = fmaf(qe[d], zp[d * 32 + lane], y);
        for (int j = 0; j < 32; ++j) {
            float s = 0.f;
#pragma unroll
            for (int d = 0; d < 32; ++d)
                s = fmaf(qe[d], vnT[d * 33 + j], s);
            if (j <= l) y = fmaf(lg[j] * s, knb[j * 32 + lane], y);
        }
        y *= wgt;
    }
    u16 hi, lo;
    split_bf16(y, hi, lo);
    const size_t oidx = ((size_t)(b * Ls + c * T + l)) * 256 + h * 32 + lane;
    chi[oidx] = hi;
    clo[oidx] = lo;
}

// ---------------- out_gemm: 32x32-tile split-bf16 MFMA, W split on the fly ----------
// grid (128,8) = 1024 blocks = 4 blocks/CU. Register-prefetch pipelined.
__global__ __launch_bounds__(256) void out_gemm(
    const u16* __restrict__ Ahi, const u16* __restrict__ Alo,
    const float* __restrict__ wo, const float* __restrict__ bo,
    float* __restrict__ out)
{
    constexpr int LDK = 40;
    __shared__ __align__(16) u16 As_hi[32 * LDK];
    __shared__ __align__(16) u16 As_lo[32 * LDK];
    __shared__ __align__(16) u16 Ws_hi[32 * LDK];
    __shared__ __align__(16) u16 Ws_lo[32 * LDK];

    const int tid = threadIdx.x;
    const int mt = blockIdx.x, nt = blockIdx.y;
    const int m0 = mt * 32, ncol0 = nt * 32;
    const int wave = tid >> 6, lane = tid & 63;
    const int l15 = lane & 15, quad = lane >> 4;
    const int srow = tid >> 2, sk = (tid & 3) * 8;   // srow 0..63: 0-31 A, 32-63 W
    const int rf = wave & 1, cf = wave >> 1;         // 2x2 of 16x16 frags

    f32x4 acc = {};

    uint4 cah, cal;
    float4 cw0, cw1;
    if (tid < 128) {
        cah = *(const uint4*)&Ahi[(size_t)(m0 + srow) * 256 + 0 + sk];
        cal = *(const uint4*)&Alo[(size_t)(m0 + srow) * 256 + 0 + sk];
    } else {
        cw0 = *(const float4*)&wo[(size_t)(ncol0 + srow - 32) * 256 + 0 + sk];
        cw1 = *(const float4*)&wo[(size_t)(ncol0 + srow - 32) * 256 + 0 + sk + 4];
    }

#pragma unroll
    for (int kk = 0; kk < 8; ++kk) {
        __syncthreads();
        if (tid < 128) {
            *(uint4*)&As_hi[srow * LDK + sk] = cah;
            *(uint4*)&As_lo[srow * LDK + sk] = cal;
        } else {
            uint4 whi, wlo;
            split8(cw0, cw1, whi, wlo);
            *(uint4*)&Ws_hi[(srow - 32) * LDK + sk] = whi;
            *(uint4*)&Ws_lo[(srow - 32) * LDK + sk] = wlo;
        }
        __syncthreads();

        if (kk < 7) {
            const int k0n = (kk + 1) * 32;
            if (tid < 128) {
                cah = *(const uint4*)&Ahi[(size_t)(m0 + srow) * 256 + k0n + sk];
                cal = *(const uint4*)&Alo[(size_t)(m0 + srow) * 256 + k0n + sk];
            } else {
                cw0 = *(const float4*)&wo[(size_t)(ncol0 + srow - 32) * 256 + k0n + sk];
                cw1 = *(const float4*)&wo[(size_t)(ncol0 + srow - 32) * 256 + k0n + sk + 4];
            }
        }

        const frag fah = *(const frag*)&As_hi[(rf * 16 + l15) * LDK + quad * 8];
        const frag fal = *(const frag*)&As_lo[(rf * 16 + l15) * LDK + quad * 8];
        const frag fbh = *(const frag*)&Ws_hi[(cf * 16 + l15) * LDK + quad * 8];
        const frag fbl = *(const frag*)&Ws_lo[(cf * 16 + l15) * LDK + quad * 8];
        acc = __builtin_amdgcn_mfma_f32_16x16x32_bf16(fah, fbh, acc, 0, 0, 0);
        acc = __builtin_amdgcn_mfma_f32_16x16x32_bf16(fah, fbl, acc, 0, 0, 0);
        acc = __builtin_amdgcn_mfma_f32_16x16x32_bf16(fal, fbh, acc, 0, 0, 0);
    }

    {
        const int o = ncol0 + cf * 16 + l15;
        const float bias = bo[o];
#pragma unroll
        for (int r = 0; r < 4; ++r) {
            const int rm = m0 + rf * 16 + quad * 4 + r;
            out[(size_t)rm * 256 + o] = acc[r] + bias;
        }
    }
}

extern "C" void kernel_launch(void* const* d_in, const int* in_sizes, int n_in,
                              void* d_out, int out_size, void* d_ws, size_t ws_size,
                              hipStream_t stream) {
    const float* x    = (const float*)d_in[0];
    const float* wq_w = (const float*)d_in[1];
    const float* wq_b = (const float*)d_in[2];
    const float* wk_w = (const float*)d_in[3];
    const float* wk_b = (const float*)d_in[4];
    const float* wv_w = (const float*)d_in[5];
    const float* wv_b = (const float*)d_in[6];
    const float* wo_w = (const float*)d_in[7];
    const float* wo_b = (const float*)d_in[8];
    const float* wg_w = (const float*)d_in[9];
    const float* wg_b = (const float*)d_in[10];
    const float* kvs  = (const float*)d_in[11];
    const float* qks  = (const float*)d_in[12];
    float* out = (float*)d_out;

    u16* chi = (u16*)d_ws;                 // 1048576 u16
    u16* clo = chi + 1048576;              // 1048576 u16
    float* qh   = (float*)(clo + 1048576); // 1048576 f32
    float* kh   = qh + 1048576;
    float* vh   = kh + 1048576;
    float* ZcT  = vh + 1048576;            // 1048576
    float* simG = ZcT + 1048576;           // 32768
    float* gG   = simG + 32768;            // 32768
    float* mT   = gG + 32768;              // 1024
    float* sT   = mT + 1024;
    float* gTt  = sT + 1024;
    float* aW   = gTt + 1024;              // 256
    float* bW   = aW + 256;                // 256
    int* flagW  = (int*)(bW + 256);
    // total ~20.5 MB

    qkv_fused<<<dim3(128, 4), 256, 0, stream>>>(
        x, wq_w, wk_w, wv_w, wq_b, wk_b, wv_b, wg_w, wg_b, kvs, qks,
        qh, kh, vh, simG, gG, ZcT, mT, sT, gTt);
    prefix_kernel<<<dim3(16, 4), 256, 0, stream>>>(
        ZcT, mT, sT, gTt, kvs, aW, bW, flagW);
    chunk_out_kernel<<<dim3(NCH, 16), 1024, 0, stream>>>(
        qh, kh, vh, simG, gG, kvs, ZcT, mT, sT, gTt, aW, bW, flagW, chi, clo);
    out_gemm<<<dim3(128, 8), 256, 0, stream>>>(
        chi, clo, wo_w, wo_b, out);
}